// Round 1
// baseline (643.553 us; speedup 1.0000x reference)
//
#include <hip/hip_runtime.h>
#include <math.h>

#define B_ 32
#define L_ 2048
#define D_ 512
#define K_ 512
#define CONC_ 100.0f
#define EPS_ 1e-12f
#define LSPLIT 16   // softmax partial chunks (128 l's each)

// ---- workspace layout (float offsets) ----
enum : size_t {
  O_SCALE = 0,                       // B*D   (accum x^2, then scale)
  O_INV   = O_SCALE + B_*D_,         // B*D
  O_BIAS  = O_INV + B_*D_,           // K
  O_MEANC = O_BIAS + K_,             // D
  O_M     = O_MEANC + D_,            // B*K
  O_RS    = O_M + (size_t)B_*K_,     // B*K  (1/sumexp)
  O_PM    = O_RS + (size_t)B_*K_,    // B*LSPLIT*K
  O_PS    = O_PM + (size_t)B_*LSPLIT*K_,
  O_W     = O_PS + (size_t)B_*LSPLIT*K_,  // B*L
  O_WX    = O_W + (size_t)B_*L_,     // B*D
  O_LOG   = O_WX + (size_t)B_*D_,    // B*L*K
  WS_FLOATS = O_LOG + (size_t)B_*L_*K_
};

// zero scale-accum and wx-accum (32768 floats)
__global__ void k_zero(float* ws) {
  int i = blockIdx.x * 256 + threadIdx.x;
  ws[O_SCALE + i] = 0.f;           // first 16384 via blocks 0..63
  // second half handled by mapping: blocks cover 32768 floats total
}

__global__ void k_zero2(float* ws) {
  int i = blockIdx.x * 256 + threadIdx.x;
  ws[O_WX + i] = 0.f;
}

// bias[k] = -CONC * ||cent[k,:]||   (one block of 64 per k)
__global__ void k_bias(const float* __restrict__ cent, float* ws) {
  int k = blockIdx.x;
  int lane = threadIdx.x;          // 0..63
  float s = 0.f;
#pragma unroll
  for (int i = 0; i < 8; ++i) {
    float c = cent[(size_t)k * D_ + lane + i * 64];
    s += c * c;
  }
#pragma unroll
  for (int off = 32; off > 0; off >>= 1) s += __shfl_down(s, off);
  if (lane == 0) ws[O_BIAS + k] = -CONC_ * sqrtf(s);
}

// meanC[d] = mean_k cent[k,d]
__global__ void k_meanc(const float* __restrict__ cent, float* ws) {
  int d = blockIdx.x * 256 + threadIdx.x;
  float s = 0.f;
  for (int k = 0; k < K_; ++k) s += cent[(size_t)k * D_ + d];
  ws[O_MEANC + d] = s * (1.f / K_);
}

// accumulate sum_l x^2 into scale  (grid: B x D/256 x 8)
__global__ void k_sqacc(const float* __restrict__ x, float* ws) {
  int b = blockIdx.x, dc = blockIdx.y, lc = blockIdx.z;
  int d = dc * 256 + threadIdx.x;
  const float* xb = x + ((size_t)b * L_ + lc * 256) * D_ + d;
  float acc = 0.f;
  for (int l = 0; l < 256; ++l) {
    float v = xb[(size_t)l * D_];
    acc += v * v;
  }
  atomicAdd(&ws[O_SCALE + b * D_ + d], acc);
}

// scale = acc/L ; inv = 1/max(scale,eps)
__global__ void k_finscale(float* ws) {
  int i = blockIdx.x * 256 + threadIdx.x;   // B*D = 16384
  float s = ws[O_SCALE + i] * (1.f / L_);
  ws[O_SCALE + i] = s;
  ws[O_INV + i] = 1.f / fmaxf(s, EPS_);
}

// logits[b,l,k] = 2C * sum_d (x[b,l,d]*inv[b,d]) * cent[k,d] + bias[k]
// 64x64 tile, BK=16, 256 threads, 4x4 microtile
__global__ __launch_bounds__(256) void k_gemm(const float* __restrict__ x,
                                              const float* __restrict__ cent,
                                              float* ws) {
  const int b = blockIdx.z;
  const int l0 = blockIdx.x * 64;
  const int k0 = blockIdx.y * 64;
  __shared__ float As[16][68];
  __shared__ float Bs[16][68];
  const int tid = threadIdx.x;
  const int tm = tid >> 4, tn = tid & 15;
  float acc[4][4] = {};
  const float* xb = x + (size_t)b * L_ * D_;
  const float* invb = ws + O_INV + b * D_;
  const float* bias = ws + O_BIAS;
  float* logits = ws + O_LOG;

  for (int d0 = 0; d0 < D_; d0 += 16) {
#pragma unroll
    for (int i = 0; i < 4; ++i) {
      int flat = tid + i * 256;
      int row = flat >> 4, col = flat & 15;
      As[col][row] = xb[(size_t)(l0 + row) * D_ + d0 + col] * invb[d0 + col];
    }
#pragma unroll
    for (int i = 0; i < 4; ++i) {
      int flat = tid + i * 256;
      int row = flat >> 4, col = flat & 15;
      Bs[col][row] = cent[(size_t)(k0 + row) * D_ + d0 + col];
    }
    __syncthreads();
#pragma unroll
    for (int kk = 0; kk < 16; ++kk) {
      float a0[4], b0[4];
#pragma unroll
      for (int i = 0; i < 4; ++i) a0[i] = As[kk][tm * 4 + i];
#pragma unroll
      for (int j = 0; j < 4; ++j) b0[j] = Bs[kk][tn * 4 + j];
#pragma unroll
      for (int i = 0; i < 4; ++i)
#pragma unroll
        for (int j = 0; j < 4; ++j) acc[i][j] += a0[i] * b0[j];
    }
    __syncthreads();
  }
  float bs[4];
#pragma unroll
  for (int j = 0; j < 4; ++j) bs[j] = bias[k0 + tn * 4 + j];
#pragma unroll
  for (int i = 0; i < 4; ++i) {
    size_t base = ((size_t)b * L_ + (l0 + tm * 4 + i)) * K_ + k0 + tn * 4;
    float4 v;
    v.x = 2.f * CONC_ * acc[i][0] + bs[0];
    v.y = 2.f * CONC_ * acc[i][1] + bs[1];
    v.z = 2.f * CONC_ * acc[i][2] + bs[2];
    v.w = 2.f * CONC_ * acc[i][3] + bs[3];
    *reinterpret_cast<float4*>(&logits[base]) = v;
  }
}

// per-(b,k) partial online softmax over 128 l's  (grid: B x LSPLIT, 512 thr)
__global__ void k_smax_part(float* ws) {
  int b = blockIdx.x, c = blockIdx.y, k = threadIdx.x;
  const float* lg = ws + O_LOG + ((size_t)b * L_ + c * 128) * K_ + k;
  float m = -INFINITY, s = 0.f;
  for (int l = 0; l < 128; ++l) {
    float v = lg[(size_t)l * K_];
    if (v > m) {
      s = s * expf(m - v) + 1.f;
      m = v;
    } else {
      s += expf(v - m);
    }
  }
  ws[O_PM + ((size_t)b * LSPLIT + c) * K_ + k] = m;
  ws[O_PS + ((size_t)b * LSPLIT + c) * K_ + k] = s;
}

// combine partials -> m, rs=1/sumexp  (grid: B, 512 thr)
__global__ void k_smax_comb(float* ws) {
  int b = blockIdx.x, k = threadIdx.x;
  float M = -INFINITY;
#pragma unroll
  for (int c = 0; c < LSPLIT; ++c)
    M = fmaxf(M, ws[O_PM + ((size_t)b * LSPLIT + c) * K_ + k]);
  float S = 0.f;
#pragma unroll
  for (int c = 0; c < LSPLIT; ++c)
    S += ws[O_PS + ((size_t)b * LSPLIT + c) * K_ + k] *
         expf(ws[O_PM + ((size_t)b * LSPLIT + c) * K_ + k] - M);
  ws[O_M + (size_t)b * K_ + k] = M;
  ws[O_RS + (size_t)b * K_ + k] = 1.f / S;
}

// w[b,l] = sum_k exp(logits-m)*rs   (grid: B*L/4 blocks, 256 thr, wave per l)
__global__ void k_wsum(float* ws) {
  int wv = threadIdx.x >> 6, lane = threadIdx.x & 63;
  int gl = blockIdx.x * 4 + wv;
  int b = gl / L_, l = gl % L_;
  const float* lg = ws + O_LOG + ((size_t)b * L_ + l) * K_;
  const float* m = ws + O_M + (size_t)b * K_;
  const float* rs = ws + O_RS + (size_t)b * K_;
  float s = 0.f;
#pragma unroll
  for (int i = 0; i < 8; ++i) {
    int k = lane + i * 64;
    s += expf(lg[k] - m[k]) * rs[k];
  }
#pragma unroll
  for (int off = 32; off > 0; off >>= 1) s += __shfl_down(s, off);
  if (lane == 0) ws[O_W + (size_t)b * L_ + l] = s;
}

// wx[b,d] += sum_l w[b,l]*x[b,l,d]   (grid: B x 2 x 8)
__global__ void k_wxacc(const float* __restrict__ x, float* ws) {
  int b = blockIdx.x, dc = blockIdx.y, lc = blockIdx.z;
  int d = dc * 256 + threadIdx.x;
  const float* xb = x + ((size_t)b * L_ + lc * 256) * D_ + d;
  const float* wb = ws + O_W + (size_t)b * L_ + lc * 256;
  float acc = 0.f;
  for (int l = 0; l < 256; ++l) acc += wb[l] * xb[(size_t)l * D_];
  atomicAdd(&ws[O_WX + b * D_ + d], acc);
}

// out[b,d] = scale * (inv*wx/K - meanC[d])
__global__ void k_final(const float* ws, float* out) {
  int i = blockIdx.x * 256 + threadIdx.x;   // B*D
  int d = i & (D_ - 1);
  out[i] = ws[O_SCALE + i] *
           (ws[O_INV + i] * ws[O_WX + i] * (1.f / K_) - ws[O_MEANC + d]);
}

extern "C" void kernel_launch(void* const* d_in, const int* in_sizes, int n_in,
                              void* d_out, int out_size, void* d_ws, size_t ws_size,
                              hipStream_t stream) {
  const float* x = (const float*)d_in[0];
  const float* cent = (const float*)d_in[1];
  float* out = (float*)d_out;
  float* ws = (float*)d_ws;

  k_zero<<<64, 256, 0, stream>>>(ws);
  k_zero2<<<64, 256, 0, stream>>>(ws);
  k_bias<<<K_, 64, 0, stream>>>(cent, ws);
  k_meanc<<<2, 256, 0, stream>>>(cent, ws);
  k_sqacc<<<dim3(B_, D_ / 256, 8), 256, 0, stream>>>(x, ws);
  k_finscale<<<B_ * D_ / 256, 256, 0, stream>>>(ws);
  k_gemm<<<dim3(L_ / 64, K_ / 64, B_), 256, 0, stream>>>(x, cent, ws);
  k_smax_part<<<dim3(B_, LSPLIT), 512, 0, stream>>>(ws);
  k_smax_comb<<<B_, 512, 0, stream>>>(ws);
  k_wsum<<<B_ * L_ / 4, 256, 0, stream>>>(ws);
  k_wxacc<<<dim3(B_, D_ / 256, 8), 256, 0, stream>>>(x, ws);
  k_final<<<B_ * D_ / 256, 256, 0, stream>>>(ws, out);
}

// Round 2
// 237.547 us; speedup vs baseline: 2.7092x; 2.7092x over previous
//
#include <hip/hip_runtime.h>
#include <math.h>

#define B_ 32
#define L_ 2048
#define D_ 512
#define K_ 512
#define CONC_ 100.0f
#define EPS_ 1e-12f
#define LSPLIT 16   // softmax partial chunks (128 l's each)

typedef __attribute__((ext_vector_type(8))) _Float16 f16x8;
typedef __attribute__((ext_vector_type(4))) _Float16 f16x4;
typedef __attribute__((ext_vector_type(4))) float f32x4;

// ---- workspace layout (float offsets) ----
enum : size_t {
  O_SCALE = 0,                       // B*D   (accum x^2, then scale)
  O_INV   = O_SCALE + B_*D_,         // B*D
  O_BIAS  = O_INV + B_*D_,           // K
  O_MEANC = O_BIAS + K_,             // D
  O_M     = O_MEANC + D_,            // B*K
  O_RS    = O_M + (size_t)B_*K_,     // B*K  (1/sumexp)
  O_PM    = O_RS + (size_t)B_*K_,    // B*LSPLIT*K
  O_PS    = O_PM + (size_t)B_*LSPLIT*K_,
  O_W     = O_PS + (size_t)B_*LSPLIT*K_,  // B*L
  O_WX    = O_W + (size_t)B_*L_,     // B*D
  O_CF16  = O_WX + B_*D_,            // K*D halfs = 131072 float slots
  O_LOG   = O_CF16 + 131072,         // B*L*K
  WS_FLOATS = O_LOG + (size_t)B_*L_*K_
};

__device__ __forceinline__ void gl2lds16(const void* gsrc, void* lds) {
  __builtin_amdgcn_global_load_lds(
      (const __attribute__((address_space(1))) void*)gsrc,
      (__attribute__((address_space(3))) void*)lds, 16, 0, 0);
}

__global__ void k_zero(float* ws) {
  int i = blockIdx.x * 256 + threadIdx.x;
  ws[O_SCALE + i] = 0.f;
}

__global__ void k_zero2(float* ws) {
  int i = blockIdx.x * 256 + threadIdx.x;
  ws[O_WX + i] = 0.f;
}

// bias[k] = -CONC * ||cent[k,:]||
__global__ void k_bias(const float* __restrict__ cent, float* ws) {
  int k = blockIdx.x;
  int lane = threadIdx.x;
  float s = 0.f;
#pragma unroll
  for (int i = 0; i < 8; ++i) {
    float c = cent[(size_t)k * D_ + lane + i * 64];
    s += c * c;
  }
#pragma unroll
  for (int off = 32; off > 0; off >>= 1) s += __shfl_down(s, off);
  if (lane == 0) ws[O_BIAS + k] = -CONC_ * sqrtf(s);
}

// meanC[d] = mean_k cent[k,d]
__global__ void k_meanc(const float* __restrict__ cent, float* ws) {
  int d = blockIdx.x * 256 + threadIdx.x;
  float s = 0.f;
  for (int k = 0; k < K_; ++k) s += cent[(size_t)k * D_ + d];
  ws[O_MEANC + d] = s * (1.f / K_);
}

// cent fp16 scaled by 2*CONC, layout [k][d]
__global__ void k_centhalf(const float* __restrict__ cent, float* ws) {
  int i = (blockIdx.x * 256 + threadIdx.x) * 4;
  float4 v = *reinterpret_cast<const float4*>(cent + i);
  f16x4 h;
  h[0] = (_Float16)(v.x * (2.f * CONC_));
  h[1] = (_Float16)(v.y * (2.f * CONC_));
  h[2] = (_Float16)(v.z * (2.f * CONC_));
  h[3] = (_Float16)(v.w * (2.f * CONC_));
  *reinterpret_cast<f16x4*>(reinterpret_cast<_Float16*>(ws + O_CF16) + i) = h;
}

// accumulate sum_l x^2 into scale
__global__ void k_sqacc(const float* __restrict__ x, float* ws) {
  int b = blockIdx.x, dc = blockIdx.y, lc = blockIdx.z;
  int d = dc * 256 + threadIdx.x;
  const float* xb = x + ((size_t)b * L_ + lc * 256) * D_ + d;
  float acc = 0.f;
  for (int l = 0; l < 256; ++l) {
    float v = xb[(size_t)l * D_];
    acc += v * v;
  }
  atomicAdd(&ws[O_SCALE + b * D_ + d], acc);
}

__global__ void k_finscale(float* ws) {
  int i = blockIdx.x * 256 + threadIdx.x;
  float s = ws[O_SCALE + i] * (1.f / L_);
  ws[O_SCALE + i] = s;
  ws[O_INV + i] = 1.f / fmaxf(s, EPS_);
}

// MFMA fp16 GEMM: logits[b,l,k] = sum_d dir[b,l,d]*(200*cent[k,d]) + bias[k]
// 128x128 tile, BK=32, 4 waves, each wave 64x64 (4x4 frags of 16x16x32)
__global__ __launch_bounds__(256) void k_gemm16(const float* __restrict__ x,
                                                float* ws) {
  const int b = blockIdx.z;
  const int l0 = blockIdx.x * 128;
  const int k0 = blockIdx.y * 128;
  __shared__ _Float16 As[128 * 32];
  __shared__ _Float16 Bs[128 * 32];
  const int tid = threadIdx.x;
  const int lane = tid & 63;
  const int w = tid >> 6;
  const int wm = w >> 1, wn = w & 1;

  const _Float16* cf = reinterpret_cast<const _Float16*>(ws + O_CF16);
  const float* invb = ws + O_INV + b * D_;
  const float* xb = x + (size_t)b * L_ * D_;

  f32x4 acc[4][4] = {};

  for (int d0 = 0; d0 < D_; d0 += 32) {
    // ---- stage B (fp16 cent) via global_load_lds, source pre-swizzled ----
#pragma unroll
    for (int r = 0; r < 2; ++r) {
      int idx16 = r * 256 + tid;           // 16-byte unit index
      int row = idx16 >> 2;                // cluster row 0..127
      int slot = idx16 & 3;
      int srccol = (slot ^ ((row >> 1) & 3)) * 8;
      const _Float16* src = cf + (size_t)(k0 + row) * D_ + d0 + srccol;
      _Float16* dst = Bs + (size_t)idx16 * 8;
      gl2lds16(src, dst);
    }
    // ---- stage A: x -> regs, *inv, cvt fp16, swizzled ds_write ----
#pragma unroll
    for (int r = 0; r < 4; ++r) {
      int f = r * 256 + tid;               // float4 unit 0..1023
      int row = f >> 3;                    // l row 0..127
      int col4 = (f & 7) << 2;             // 0,4,..,28
      float4 xv = *reinterpret_cast<const float4*>(
          xb + (size_t)(l0 + row) * D_ + d0 + col4);
      float4 iv = *reinterpret_cast<const float4*>(invb + d0 + col4);
      f16x4 hv;
      hv[0] = (_Float16)(xv.x * iv.x);
      hv[1] = (_Float16)(xv.y * iv.y);
      hv[2] = (_Float16)(xv.z * iv.z);
      hv[3] = (_Float16)(xv.w * iv.w);
      int slot = col4 >> 3;
      int half = (col4 >> 2) & 1;
      int sw = slot ^ ((row >> 1) & 3);
      *reinterpret_cast<f16x4*>(
          reinterpret_cast<char*>(As) + row * 64 + sw * 16 + half * 8) = hv;
    }
    __syncthreads();

    f16x8 af[4], bfr[4];
#pragma unroll
    for (int mi = 0; mi < 4; ++mi) {
      int row = wm * 64 + mi * 16 + (lane & 15);
      int sw = (lane >> 4) ^ ((row >> 1) & 3);
      af[mi] = *reinterpret_cast<const f16x8*>(
          reinterpret_cast<const char*>(As) + row * 64 + sw * 16);
    }
#pragma unroll
    for (int ni = 0; ni < 4; ++ni) {
      int row = wn * 64 + ni * 16 + (lane & 15);
      int sw = (lane >> 4) ^ ((row >> 1) & 3);
      bfr[ni] = *reinterpret_cast<const f16x8*>(
          reinterpret_cast<const char*>(Bs) + row * 64 + sw * 16);
    }
#pragma unroll
    for (int mi = 0; mi < 4; ++mi)
#pragma unroll
      for (int ni = 0; ni < 4; ++ni)
        acc[mi][ni] = __builtin_amdgcn_mfma_f32_16x16x32_f16(
            af[mi], bfr[ni], acc[mi][ni], 0, 0, 0);
    __syncthreads();
  }

  // epilogue: + bias, store fp32 logits
  const float* bias = ws + O_BIAS;
  float* logits = ws + O_LOG + (size_t)b * L_ * K_;
#pragma unroll
  for (int ni = 0; ni < 4; ++ni) {
    int kcol = k0 + wn * 64 + ni * 16 + (lane & 15);
    float bv = bias[kcol];
#pragma unroll
    for (int mi = 0; mi < 4; ++mi) {
      int lrow0 = l0 + wm * 64 + mi * 16 + (lane >> 4) * 4;
#pragma unroll
      for (int j = 0; j < 4; ++j) {
        logits[(size_t)(lrow0 + j) * K_ + kcol] = acc[mi][ni][j] + bv;
      }
    }
  }
}

// per-(b,k) partial online softmax over 128 l's
__global__ void k_smax_part(float* ws) {
  int b = blockIdx.x, c = blockIdx.y, k = threadIdx.x;
  const float* lg = ws + O_LOG + ((size_t)b * L_ + c * 128) * K_ + k;
  float m = -INFINITY, s = 0.f;
  for (int l = 0; l < 128; ++l) {
    float v = lg[(size_t)l * K_];
    if (v > m) {
      s = s * expf(m - v) + 1.f;
      m = v;
    } else {
      s += expf(v - m);
    }
  }
  ws[O_PM + ((size_t)b * LSPLIT + c) * K_ + k] = m;
  ws[O_PS + ((size_t)b * LSPLIT + c) * K_ + k] = s;
}

__global__ void k_smax_comb(float* ws) {
  int b = blockIdx.x, k = threadIdx.x;
  float M = -INFINITY;
#pragma unroll
  for (int c = 0; c < LSPLIT; ++c)
    M = fmaxf(M, ws[O_PM + ((size_t)b * LSPLIT + c) * K_ + k]);
  float S = 0.f;
#pragma unroll
  for (int c = 0; c < LSPLIT; ++c)
    S += ws[O_PS + ((size_t)b * LSPLIT + c) * K_ + k] *
         expf(ws[O_PM + ((size_t)b * LSPLIT + c) * K_ + k] - M);
  ws[O_M + (size_t)b * K_ + k] = M;
  ws[O_RS + (size_t)b * K_ + k] = 1.f / S;
}

// w[b,l] = sum_k exp(logits-m)*rs
__global__ void k_wsum(float* ws) {
  int wv = threadIdx.x >> 6, lane = threadIdx.x & 63;
  int gl = blockIdx.x * 4 + wv;
  int b = gl / L_, l = gl % L_;
  const float* lg = ws + O_LOG + ((size_t)b * L_ + l) * K_;
  const float* m = ws + O_M + (size_t)b * K_;
  const float* rs = ws + O_RS + (size_t)b * K_;
  float s = 0.f;
#pragma unroll
  for (int i = 0; i < 8; ++i) {
    int k = lane + i * 64;
    s += expf(lg[k] - m[k]) * rs[k];
  }
#pragma unroll
  for (int off = 32; off > 0; off >>= 1) s += __shfl_down(s, off);
  if (lane == 0) ws[O_W + (size_t)b * L_ + l] = s;
}

// wx[b,d] += sum_l w[b,l]*x[b,l,d]
__global__ void k_wxacc(const float* __restrict__ x, float* ws) {
  int b = blockIdx.x, dc = blockIdx.y, lc = blockIdx.z;
  int d = dc * 256 + threadIdx.x;
  const float* xb = x + ((size_t)b * L_ + lc * 256) * D_ + d;
  const float* wb = ws + O_W + (size_t)b * L_ + lc * 256;
  float acc = 0.f;
  for (int l = 0; l < 256; ++l) acc += wb[l] * xb[(size_t)l * D_];
  atomicAdd(&ws[O_WX + b * D_ + d], acc);
}

// out[b,d] = scale * (inv*wx/K - meanC[d])
__global__ void k_final(const float* ws, float* out) {
  int i = blockIdx.x * 256 + threadIdx.x;
  int d = i & (D_ - 1);
  out[i] = ws[O_SCALE + i] *
           (ws[O_INV + i] * ws[O_WX + i] * (1.f / K_) - ws[O_MEANC + d]);
}

extern "C" void kernel_launch(void* const* d_in, const int* in_sizes, int n_in,
                              void* d_out, int out_size, void* d_ws, size_t ws_size,
                              hipStream_t stream) {
  const float* x = (const float*)d_in[0];
  const float* cent = (const float*)d_in[1];
  float* out = (float*)d_out;
  float* ws = (float*)d_ws;

  k_zero<<<64, 256, 0, stream>>>(ws);
  k_zero2<<<64, 256, 0, stream>>>(ws);
  k_bias<<<K_, 64, 0, stream>>>(cent, ws);
  k_meanc<<<2, 256, 0, stream>>>(cent, ws);
  k_centhalf<<<256, 256, 0, stream>>>(cent, ws);
  k_sqacc<<<dim3(B_, D_ / 256, 8), 256, 0, stream>>>(x, ws);
  k_finscale<<<B_ * D_ / 256, 256, 0, stream>>>(ws);
  k_gemm16<<<dim3(L_ / 128, K_ / 128, B_), 256, 0, stream>>>(x, ws);
  k_smax_part<<<dim3(B_, LSPLIT), 512, 0, stream>>>(ws);
  k_smax_comb<<<B_, 512, 0, stream>>>(ws);
  k_wsum<<<B_ * L_ / 4, 256, 0, stream>>>(ws);
  k_wxacc<<<dim3(B_, D_ / 256, 8), 256, 0, stream>>>(x, ws);
  k_final<<<B_ * D_ / 256, 256, 0, stream>>>(ws, out);
}

// Round 4
// 209.937 us; speedup vs baseline: 3.0655x; 1.1315x over previous
//
#include <hip/hip_runtime.h>
#include <math.h>

#define B_ 32
#define L_ 2048
#define D_ 512
#define K_ 512
#define CONC_ 100.0f
#define EPS_ 1e-12f
#define LSPLIT 16   // 16 chunks of 128 l's (= GEMM l-tile)

typedef __attribute__((ext_vector_type(8))) _Float16 f16x8;
typedef __attribute__((ext_vector_type(4))) _Float16 f16x4;
typedef __attribute__((ext_vector_type(2))) _Float16 f16x2;
typedef __attribute__((ext_vector_type(4))) float f32x4;

// ---- workspace layout (float offsets) ----
enum : size_t {
  O_SCALE = 0,                          // B*D
  O_INV   = O_SCALE + B_*D_,            // B*D
  O_MEANC = O_INV + B_*D_,              // D
  O_PM    = O_MEANC + D_,               // B*LSPLIT*K  (chunk max -> A coeff)
  O_PS    = O_PM + (size_t)B_*LSPLIT*K_,// B*LSPLIT*K  (chunk sum)
  O_WX    = O_PS + (size_t)B_*LSPLIT*K_,// B*D
  O_CF16  = O_WX + B_*D_,               // K*D halfs   = 131072 floats
  O_DIR   = O_CF16 + (size_t)K_*D_/2,   // B*L*D halfs = 16777216 floats
  O_L16   = O_DIR + (size_t)B_*L_*D_/2, // B*L*K halfs (shifted logits)
  WS_FLOATS = O_L16 + (size_t)B_*L_*K_/2
};

__device__ __forceinline__ void gl2lds16(const void* gsrc, void* lds) {
  __builtin_amdgcn_global_load_lds(
      (const __attribute__((address_space(1))) void*)gsrc,
      (__attribute__((address_space(3))) void*)lds, 16, 0, 0);
}

__global__ void k_zero(float* ws) {
  int i = blockIdx.x * 256 + threadIdx.x;
  ws[O_SCALE + i] = 0.f;
}

__global__ void k_zero2(float* ws) {
  int i = blockIdx.x * 256 + threadIdx.x;
  ws[O_WX + i] = 0.f;
}

// meanC[d] = mean_k cent[k,d]
__global__ void k_meanc(const float* __restrict__ cent, float* ws) {
  int d = blockIdx.x * 256 + threadIdx.x;
  float s = 0.f;
  for (int k = 0; k < K_; ++k) s += cent[(size_t)k * D_ + d];
  ws[O_MEANC + d] = s * (1.f / K_);
}

// cent fp16 scaled by 2*CONC, layout [k][d]
__global__ void k_centhalf(const float* __restrict__ cent, float* ws) {
  int i = (blockIdx.x * 256 + threadIdx.x) * 4;
  float4 v = *reinterpret_cast<const float4*>(cent + i);
  f16x4 h;
  h[0] = (_Float16)(v.x * (2.f * CONC_));
  h[1] = (_Float16)(v.y * (2.f * CONC_));
  h[2] = (_Float16)(v.z * (2.f * CONC_));
  h[3] = (_Float16)(v.w * (2.f * CONC_));
  *reinterpret_cast<f16x4*>(reinterpret_cast<_Float16*>(ws + O_CF16) + i) = h;
}

// accumulate sum_l x^2 into scale
__global__ void k_sqacc(const float* __restrict__ x, float* ws) {
  int b = blockIdx.x, dc = blockIdx.y, lc = blockIdx.z;
  int d = dc * 256 + threadIdx.x;
  const float* xb = x + ((size_t)b * L_ + lc * 256) * D_ + d;
  float acc = 0.f;
  for (int l = 0; l < 256; ++l) {
    float v = xb[(size_t)l * D_];
    acc += v * v;
  }
  atomicAdd(&ws[O_SCALE + b * D_ + d], acc);
}

__global__ void k_finscale(float* ws) {
  int i = blockIdx.x * 256 + threadIdx.x;
  float s = ws[O_SCALE + i] * (1.f / L_);
  ws[O_SCALE + i] = s;
  ws[O_INV + i] = 1.f / fmaxf(s, EPS_);
}

// dir16[b,l,d] = fp16(x * inv), linear layout  (2^25 elems / 8 per thread)
__global__ void k_dir16(const float* __restrict__ x, float* ws) {
  size_t i = ((size_t)blockIdx.x * 256 + threadIdx.x) * 8;
  int d8 = (int)(i & (D_ - 1));
  int b = (int)(i >> 20);                 // L_*D_ = 2^20
  float4 x0 = *reinterpret_cast<const float4*>(x + i);
  float4 x1 = *reinterpret_cast<const float4*>(x + i + 4);
  const float* invb = ws + O_INV + (size_t)b * D_ + d8;
  float4 v0 = *reinterpret_cast<const float4*>(invb);
  float4 v1 = *reinterpret_cast<const float4*>(invb + 4);
  f16x8 h;
  h[0] = (_Float16)(x0.x * v0.x); h[1] = (_Float16)(x0.y * v0.y);
  h[2] = (_Float16)(x0.z * v0.z); h[3] = (_Float16)(x0.w * v0.w);
  h[4] = (_Float16)(x1.x * v1.x); h[5] = (_Float16)(x1.y * v1.y);
  h[6] = (_Float16)(x1.z * v1.z); h[7] = (_Float16)(x1.w * v1.w);
  *reinterpret_cast<f16x8*>(reinterpret_cast<_Float16*>(ws + O_DIR) + i) = h;
}

// MFMA GEMM + fused per-chunk softmax partials + fp16 shifted-logit store.
// 128x128 tile, BK=32, 4 waves, each wave 64x64 (4x4 frags of 16x16x32).
__global__ __launch_bounds__(256) void k_gemm16(float* ws) {
  const int b = blockIdx.z;
  const int l0 = blockIdx.x * 128;
  const int k0 = blockIdx.y * 128;
  __shared__ _Float16 As[128 * 32];
  __shared__ _Float16 Bs[128 * 32];
  const int tid = threadIdx.x;
  const int lane = tid & 63;
  const int w = tid >> 6;
  const int wm = w >> 1, wn = w & 1;

  const _Float16* cf = reinterpret_cast<const _Float16*>(ws + O_CF16);
  const _Float16* db = reinterpret_cast<const _Float16*>(ws + O_DIR) +
                       (size_t)b * L_ * D_;

  f32x4 acc[4][4] = {};

  for (int d0 = 0; d0 < D_; d0 += 32) {
    // stage A (dir16) and B (cent16) via global_load_lds, sources pre-swizzled
#pragma unroll
    for (int r = 0; r < 2; ++r) {
      int u = r * 256 + tid;               // 16B unit 0..511
      int row = u >> 2;
      int slot = u & 3;
      int sc = (slot ^ ((row >> 1) & 3)) * 8;
      gl2lds16(db + (size_t)(l0 + row) * D_ + d0 + sc, As + (size_t)u * 8);
    }
#pragma unroll
    for (int r = 0; r < 2; ++r) {
      int u = r * 256 + tid;
      int row = u >> 2;
      int slot = u & 3;
      int sc = (slot ^ ((row >> 1) & 3)) * 8;
      gl2lds16(cf + (size_t)(k0 + row) * D_ + d0 + sc, Bs + (size_t)u * 8);
    }
    __syncthreads();

    f16x8 af[4], bfr[4];
#pragma unroll
    for (int mi = 0; mi < 4; ++mi) {
      int row = wm * 64 + mi * 16 + (lane & 15);
      int sw = (lane >> 4) ^ ((row >> 1) & 3);
      af[mi] = *reinterpret_cast<const f16x8*>(
          reinterpret_cast<const char*>(As) + row * 64 + sw * 16);
    }
#pragma unroll
    for (int ni = 0; ni < 4; ++ni) {
      int row = wn * 64 + ni * 16 + (lane & 15);
      int sw = (lane >> 4) ^ ((row >> 1) & 3);
      bfr[ni] = *reinterpret_cast<const f16x8*>(
          reinterpret_cast<const char*>(Bs) + row * 64 + sw * 16);
    }
#pragma unroll
    for (int mi = 0; mi < 4; ++mi)
#pragma unroll
      for (int ni = 0; ni < 4; ++ni)
        acc[mi][ni] = __builtin_amdgcn_mfma_f32_16x16x32_f16(
            af[mi], bfr[ni], acc[mi][ni], 0, 0, 0);
    __syncthreads();
  }

  // ---- fused softmax partials over this block's 128 l's ----
  // (bias[k] omitted: constant over l, cancels in softmax over l)
  float* red = reinterpret_cast<float*>(As);   // [2][128] wave maxes
  float* red2 = red + 256;                     // [2][128] wave sums
  float pm[4], ps[4];
#pragma unroll
  for (int ni = 0; ni < 4; ++ni) {
    float m = -INFINITY;
#pragma unroll
    for (int mi = 0; mi < 4; ++mi)
#pragma unroll
      for (int j = 0; j < 4; ++j) m = fmaxf(m, acc[mi][ni][j]);
    m = fmaxf(m, __shfl_xor(m, 16));
    m = fmaxf(m, __shfl_xor(m, 32));
    pm[ni] = m;
  }
  if (lane < 16) {
#pragma unroll
    for (int ni = 0; ni < 4; ++ni)
      red[wm * 128 + wn * 64 + ni * 16 + lane] = pm[ni];
  }
  __syncthreads();
#pragma unroll
  for (int ni = 0; ni < 4; ++ni) {
    int idx = wn * 64 + ni * 16 + (lane & 15);
    pm[ni] = fmaxf(red[idx], red[128 + idx]);   // combined chunk max
  }
#pragma unroll
  for (int ni = 0; ni < 4; ++ni) {
    float s = 0.f;
#pragma unroll
    for (int mi = 0; mi < 4; ++mi)
#pragma unroll
      for (int j = 0; j < 4; ++j) s += expf(acc[mi][ni][j] - pm[ni]);
    s += __shfl_xor(s, 16);
    s += __shfl_xor(s, 32);
    ps[ni] = s;
  }
  if (lane < 16) {
#pragma unroll
    for (int ni = 0; ni < 4; ++ni)
      red2[wm * 128 + wn * 64 + ni * 16 + lane] = ps[ni];
  }
  __syncthreads();
  if (w < 2 && lane < 16) {                     // waves wm==0 write partials
#pragma unroll
    for (int ni = 0; ni < 4; ++ni) {
      int idx = wn * 64 + ni * 16 + lane;
      float mg = fmaxf(red[idx], red[128 + idx]);
      float sg = red2[idx] + red2[128 + idx];
      size_t o = ((size_t)b * LSPLIT + blockIdx.x) * K_ + k0 + idx;
      ws[O_PM + o] = mg;
      ws[O_PS + o] = sg;
    }
  }
  // store fp16 shifted logits (v - chunk_max), linear [b][l][k]
  _Float16* lg = reinterpret_cast<_Float16*>(ws + O_L16) + (size_t)b * L_ * K_;
#pragma unroll
  for (int ni = 0; ni < 4; ++ni) {
    int kc = k0 + wn * 64 + ni * 16 + (lane & 15);
#pragma unroll
    for (int mi = 0; mi < 4; ++mi) {
      int lr = l0 + wm * 64 + mi * 16 + (lane >> 4) * 4;
#pragma unroll
      for (int j = 0; j < 4; ++j)
        lg[(size_t)(lr + j) * K_ + kc] = (_Float16)(acc[mi][ni][j] - pm[ni]);
    }
  }
}

// combine chunk partials -> A[b,chunk,k] = exp(m_c - M) / S  (in place in O_PM)
__global__ void k_smax_comb(float* ws) {
  int b = blockIdx.x, k = threadIdx.x;   // 512 threads
  float pmv[LSPLIT], psv[LSPLIT];
  float M = -INFINITY;
#pragma unroll
  for (int c = 0; c < LSPLIT; ++c) {
    pmv[c] = ws[O_PM + ((size_t)b * LSPLIT + c) * K_ + k];
    psv[c] = ws[O_PS + ((size_t)b * LSPLIT + c) * K_ + k];
    M = fmaxf(M, pmv[c]);
  }
  float S = 0.f;
#pragma unroll
  for (int c = 0; c < LSPLIT; ++c) S += psv[c] * expf(pmv[c] - M);
  float rs = 1.f / S;
#pragma unroll
  for (int c = 0; c < LSPLIT; ++c)
    ws[O_PM + ((size_t)b * LSPLIT + c) * K_ + k] = expf(pmv[c] - M) * rs;
}

// fused: w[l] = sum_k exp(vshift[l,k])*A[k]; then wx[b,d] += sum_l w[l]*dir[l,d]
__global__ __launch_bounds__(256) void k_wsumwx(float* ws) {
  int b = blockIdx.x, ch = blockIdx.y;
  int l0 = ch * 128;
  __shared__ float wl[128];
  __shared__ float Al[512];
  int tid = threadIdx.x, lane = tid & 63, wv = tid >> 6;
  size_t abase = O_PM + ((size_t)b * LSPLIT + ch) * K_;
  Al[tid] = ws[abase + tid];
  Al[256 + tid] = ws[abase + 256 + tid];
  __syncthreads();

  const _Float16* lg = reinterpret_cast<const _Float16*>(ws + O_L16) +
                       (size_t)(b * L_ + l0) * K_;
  float a8[8];
#pragma unroll
  for (int i = 0; i < 8; ++i) a8[i] = Al[lane * 8 + i];

  for (int il = 0; il < 32; ++il) {
    int ll = wv * 32 + il;
    f16x8 v = *reinterpret_cast<const f16x8*>(lg + (size_t)ll * K_ + lane * 8);
    float s = 0.f;
#pragma unroll
    for (int i = 0; i < 8; ++i) s += expf((float)v[i]) * a8[i];
#pragma unroll
    for (int off = 32; off > 0; off >>= 1) s += __shfl_xor(s, off);
    if (lane == 0) wl[ll] = s;
  }
  __syncthreads();

  const _Float16* db = reinterpret_cast<const _Float16*>(ws + O_DIR) +
                       (size_t)(b * L_ + l0) * D_;
  int half = tid >> 7;            // 0/1 -> l 0..63 / 64..127
  int dd = (tid & 127) * 4;
  float4 a4 = {0.f, 0.f, 0.f, 0.f};
  for (int l = half * 64; l < half * 64 + 64; ++l) {
    float wgt = wl[l];
    f16x4 dv = *reinterpret_cast<const f16x4*>(db + (size_t)l * D_ + dd);
    a4.x += wgt * (float)dv[0];
    a4.y += wgt * (float)dv[1];
    a4.z += wgt * (float)dv[2];
    a4.w += wgt * (float)dv[3];
  }
  atomicAdd(&ws[O_WX + b * D_ + dd + 0], a4.x);
  atomicAdd(&ws[O_WX + b * D_ + dd + 1], a4.y);
  atomicAdd(&ws[O_WX + b * D_ + dd + 2], a4.z);
  atomicAdd(&ws[O_WX + b * D_ + dd + 3], a4.w);
}

// out[b,d] = scale * (wx/K - meanC[d])   (wx already includes inv via dir16)
__global__ void k_final(const float* ws, float* out) {
  int i = blockIdx.x * 256 + threadIdx.x;
  int d = i & (D_ - 1);
  out[i] = ws[O_SCALE + i] *
           (ws[O_WX + i] * (1.f / K_) - ws[O_MEANC + d]);
}

extern "C" void kernel_launch(void* const* d_in, const int* in_sizes, int n_in,
                              void* d_out, int out_size, void* d_ws, size_t ws_size,
                              hipStream_t stream) {
  const float* x = (const float*)d_in[0];
  const float* cent = (const float*)d_in[1];
  float* out = (float*)d_out;
  float* ws = (float*)d_ws;

  k_zero<<<64, 256, 0, stream>>>(ws);
  k_zero2<<<64, 256, 0, stream>>>(ws);
  k_meanc<<<2, 256, 0, stream>>>(cent, ws);
  k_centhalf<<<256, 256, 0, stream>>>(cent, ws);
  k_sqacc<<<dim3(B_, D_ / 256, 8), 256, 0, stream>>>(x, ws);
  k_finscale<<<B_ * D_ / 256, 256, 0, stream>>>(ws);
  k_dir16<<<16384, 256, 0, stream>>>(x, ws);   // 2^25 elems / 8 / 256
  k_gemm16<<<dim3(L_ / 128, K_ / 128, B_), 256, 0, stream>>>(ws);
  k_smax_comb<<<B_, 512, 0, stream>>>(ws);
  k_wsumwx<<<dim3(B_, LSPLIT), 256, 0, stream>>>(ws);
  k_final<<<B_ * D_ / 256, 256, 0, stream>>>(ws, out);
}

// Round 5
// 193.110 us; speedup vs baseline: 3.3326x; 1.0871x over previous
//
#include <hip/hip_runtime.h>
#include <math.h>

#define B_ 32
#define L_ 2048
#define D_ 512
#define K_ 512
#define CONC_ 100.0f
#define EPS_ 1e-12f
#define LSPLIT 16   // 16 chunks of 128 l's (= GEMM l-tile)

typedef __attribute__((ext_vector_type(8))) _Float16 f16x8;
typedef __attribute__((ext_vector_type(4))) _Float16 f16x4;
typedef __attribute__((ext_vector_type(4))) float f32x4;

// ---- workspace layout (float offsets) ----
enum : size_t {
  O_SCALE = 0,                          // B*D  (raw sum_l x^2, accumulated)
  O_MEANC = O_SCALE + B_*D_,            // D
  O_PM    = O_MEANC + D_,               // B*LSPLIT*K  (chunk max)
  O_PS    = O_PM + (size_t)B_*LSPLIT*K_,// B*LSPLIT*K  (chunk sum)
  O_WX    = O_PS + (size_t)B_*LSPLIT*K_,// B*D
  O_CF16  = O_WX + B_*D_,               // K*D halfs   = 131072 floats
  O_DIR   = O_CF16 + (size_t)K_*D_/2,   // B*L*D halfs
  O_L16   = O_DIR + (size_t)B_*L_*D_/2, // B*L*K halfs (shifted logits)
  WS_FLOATS = O_L16 + (size_t)B_*L_*K_/2
};

__device__ __forceinline__ void gl2lds16(const void* gsrc, void* lds) {
  __builtin_amdgcn_global_load_lds(
      (const __attribute__((address_space(1))) void*)gsrc,
      (__attribute__((address_space(3))) void*)lds, 16, 0, 0);
}

// merged prep: centhalf (blocks 0..255), meanc (256..257),
// zero scale (258..321), zero wx (322..385)
__global__ void k_prep(const float* __restrict__ cent, float* ws) {
  int blk = blockIdx.x, tid = threadIdx.x;
  if (blk < 256) {
    int i = (blk * 256 + tid) * 4;
    float4 v = *reinterpret_cast<const float4*>(cent + i);
    f16x4 h;
    h[0] = (_Float16)(v.x * (2.f * CONC_));
    h[1] = (_Float16)(v.y * (2.f * CONC_));
    h[2] = (_Float16)(v.z * (2.f * CONC_));
    h[3] = (_Float16)(v.w * (2.f * CONC_));
    *reinterpret_cast<f16x4*>(reinterpret_cast<_Float16*>(ws + O_CF16) + i) = h;
  } else if (blk < 258) {
    int d = (blk - 256) * 256 + tid;
    float s = 0.f;
    for (int k = 0; k < K_; ++k) s += cent[(size_t)k * D_ + d];
    ws[O_MEANC + d] = s * (1.f / K_);
  } else if (blk < 322) {
    ws[O_SCALE + (blk - 258) * 256 + tid] = 0.f;
  } else {
    ws[O_WX + (blk - 322) * 256 + tid] = 0.f;
  }
}

// accumulate sum_l x^2 into scale (raw, not divided)
__global__ void k_sqacc(const float* __restrict__ x, float* ws) {
  int b = blockIdx.x, dc = blockIdx.y, lc = blockIdx.z;
  int d = dc * 256 + threadIdx.x;
  const float* xb = x + ((size_t)b * L_ + lc * 256) * D_ + d;
  float acc = 0.f;
  for (int l = 0; l < 256; ++l) {
    float v = xb[(size_t)l * D_];
    acc += v * v;
  }
  atomicAdd(&ws[O_SCALE + b * D_ + d], acc);
}

// dir16[b,l,d] = fp16(x / max(scale,eps)), inv computed on the fly
__global__ void k_dir16(const float* __restrict__ x, float* ws) {
  size_t i = ((size_t)blockIdx.x * 256 + threadIdx.x) * 8;
  int d8 = (int)(i & (D_ - 1));
  int b = (int)(i >> 20);                 // L_*D_ = 2^20
  float4 x0 = *reinterpret_cast<const float4*>(x + i);
  float4 x1 = *reinterpret_cast<const float4*>(x + i + 4);
  const float* sb = ws + O_SCALE + (size_t)b * D_ + d8;
  float4 s0 = *reinterpret_cast<const float4*>(sb);
  float4 s1 = *reinterpret_cast<const float4*>(sb + 4);
  f16x8 h;
  h[0] = (_Float16)(x0.x / fmaxf(s0.x * (1.f / L_), EPS_));
  h[1] = (_Float16)(x0.y / fmaxf(s0.y * (1.f / L_), EPS_));
  h[2] = (_Float16)(x0.z / fmaxf(s0.z * (1.f / L_), EPS_));
  h[3] = (_Float16)(x0.w / fmaxf(s0.w * (1.f / L_), EPS_));
  h[4] = (_Float16)(x1.x / fmaxf(s1.x * (1.f / L_), EPS_));
  h[5] = (_Float16)(x1.y / fmaxf(s1.y * (1.f / L_), EPS_));
  h[6] = (_Float16)(x1.z / fmaxf(s1.z * (1.f / L_), EPS_));
  h[7] = (_Float16)(x1.w / fmaxf(s1.w * (1.f / L_), EPS_));
  *reinterpret_cast<f16x8*>(reinterpret_cast<_Float16*>(ws + O_DIR) + i) = h;
}

// MFMA GEMM + fused per-chunk softmax partials + fp16 shifted-logit store.
// 128x128 tile, BK=32, 4 waves; 2-phase double-buffered LDS (prefetch next
// K-step before computing current; one barrier per step).
__global__ __launch_bounds__(256) void k_gemm16(float* ws) {
  const int b = blockIdx.z;
  const int l0 = blockIdx.x * 128;
  const int k0 = blockIdx.y * 128;
  __shared__ _Float16 As[2][128 * 32];
  __shared__ _Float16 Bs[2][128 * 32];
  const int tid = threadIdx.x;
  const int lane = tid & 63;
  const int w = tid >> 6;
  const int wm = w >> 1, wn = w & 1;

  const _Float16* cf = reinterpret_cast<const _Float16*>(ws + O_CF16);
  const _Float16* db = reinterpret_cast<const _Float16*>(ws + O_DIR) +
                       (size_t)b * L_ * D_;

  // precompute the per-thread staging indices (same for both A and B)
  const int u0 = tid;            // unit 0..255
  const int u1 = 256 + tid;      // unit 256..511
  const int row0 = u0 >> 2, sc0 = ((u0 & 3) ^ ((row0 >> 1) & 3)) * 8;
  const int row1 = u1 >> 2, sc1 = ((u1 & 3) ^ ((row1 >> 1) & 3)) * 8;

  f32x4 acc[4][4] = {};

#define STAGE(buf, d0)                                                        \
  {                                                                           \
    gl2lds16(db + (size_t)(l0 + row0) * D_ + (d0) + sc0, &As[buf][u0 * 8]);   \
    gl2lds16(db + (size_t)(l0 + row1) * D_ + (d0) + sc1, &As[buf][u1 * 8]);   \
    gl2lds16(cf + (size_t)(k0 + row0) * D_ + (d0) + sc0, &Bs[buf][u0 * 8]);   \
    gl2lds16(cf + (size_t)(k0 + row1) * D_ + (d0) + sc1, &Bs[buf][u1 * 8]);   \
  }

  STAGE(0, 0);
  __syncthreads();

  int cur = 0;
#pragma unroll 2
  for (int t = 0; t < 16; ++t) {
    if (t < 15) STAGE(cur ^ 1, (t + 1) * 32);   // prefetch next K-step

    f16x8 af[4], bfr[4];
#pragma unroll
    for (int mi = 0; mi < 4; ++mi) {
      int row = wm * 64 + mi * 16 + (lane & 15);
      int sw = (lane >> 4) ^ ((row >> 1) & 3);
      af[mi] = *reinterpret_cast<const f16x8*>(
          reinterpret_cast<const char*>(As[cur]) + row * 64 + sw * 16);
    }
#pragma unroll
    for (int ni = 0; ni < 4; ++ni) {
      int row = wn * 64 + ni * 16 + (lane & 15);
      int sw = (lane >> 4) ^ ((row >> 1) & 3);
      bfr[ni] = *reinterpret_cast<const f16x8*>(
          reinterpret_cast<const char*>(Bs[cur]) + row * 64 + sw * 16);
    }
#pragma unroll
    for (int mi = 0; mi < 4; ++mi)
#pragma unroll
      for (int ni = 0; ni < 4; ++ni)
        acc[mi][ni] = __builtin_amdgcn_mfma_f32_16x16x32_f16(
            af[mi], bfr[ni], acc[mi][ni], 0, 0, 0);
    __syncthreads();   // drains vmcnt (next stage done) + all reads of cur
    cur ^= 1;
  }
#undef STAGE

  // ---- fused softmax partials over this block's 128 l's ----
  // (bias[k] omitted: constant over l, cancels in softmax over l)
  float* red = reinterpret_cast<float*>(As);   // [2][128] wave maxes
  float* red2 = red + 256;                     // [2][128] wave sums
  float pm[4], ps[4];
#pragma unroll
  for (int ni = 0; ni < 4; ++ni) {
    float m = -INFINITY;
#pragma unroll
    for (int mi = 0; mi < 4; ++mi)
#pragma unroll
      for (int j = 0; j < 4; ++j) m = fmaxf(m, acc[mi][ni][j]);
    m = fmaxf(m, __shfl_xor(m, 16));
    m = fmaxf(m, __shfl_xor(m, 32));
    pm[ni] = m;
  }
  if (lane < 16) {
#pragma unroll
    for (int ni = 0; ni < 4; ++ni)
      red[wm * 128 + wn * 64 + ni * 16 + lane] = pm[ni];
  }
  __syncthreads();
#pragma unroll
  for (int ni = 0; ni < 4; ++ni) {
    int idx = wn * 64 + ni * 16 + (lane & 15);
    pm[ni] = fmaxf(red[idx], red[128 + idx]);   // combined chunk max
  }
#pragma unroll
  for (int ni = 0; ni < 4; ++ni) {
    float s = 0.f;
#pragma unroll
    for (int mi = 0; mi < 4; ++mi)
#pragma unroll
      for (int j = 0; j < 4; ++j) s += expf(acc[mi][ni][j] - pm[ni]);
    s += __shfl_xor(s, 16);
    s += __shfl_xor(s, 32);
    ps[ni] = s;
  }
  if (lane < 16) {
#pragma unroll
    for (int ni = 0; ni < 4; ++ni)
      red2[wm * 128 + wn * 64 + ni * 16 + lane] = ps[ni];
  }
  __syncthreads();
  if (w < 2 && lane < 16) {
#pragma unroll
    for (int ni = 0; ni < 4; ++ni) {
      int idx = wn * 64 + ni * 16 + lane;
      float mg = fmaxf(red[idx], red[128 + idx]);
      float sg = red2[idx] + red2[128 + idx];
      size_t o = ((size_t)b * LSPLIT + blockIdx.x) * K_ + k0 + idx;
      ws[O_PM + o] = mg;
      ws[O_PS + o] = sg;
    }
  }
  // store fp16 shifted logits (v - chunk_max), linear [b][l][k]
  _Float16* lg = reinterpret_cast<_Float16*>(ws + O_L16) + (size_t)b * L_ * K_;
#pragma unroll
  for (int ni = 0; ni < 4; ++ni) {
    int kc = k0 + wn * 64 + ni * 16 + (lane & 15);
#pragma unroll
    for (int mi = 0; mi < 4; ++mi) {
      int lr = l0 + wm * 64 + mi * 16 + (lane >> 4) * 4;
#pragma unroll
      for (int j = 0; j < 4; ++j)
        lg[(size_t)(lr + j) * K_ + kc] = (_Float16)(acc[mi][ni][j] - pm[ni]);
    }
  }
}

// fused: recompute chunk->global combine (read-only PM/PS), then
// w[l] = sum_k exp(vshift[l,k])*A[k]; then wx[b,d] += sum_l w[l]*dir[l,d]
__global__ __launch_bounds__(256) void k_wsumwx(float* ws) {
  int b = blockIdx.x, ch = blockIdx.y;
  int l0 = ch * 128;
  __shared__ float wl[128];
  __shared__ float Al[512];
  int tid = threadIdx.x, lane = tid & 63, wv = tid >> 6;

  // combine: A[k] = exp(pm[ch,k] - M[k]) / S[k]
  for (int kk = tid; kk < K_; kk += 256) {
    float pmv[LSPLIT], psv[LSPLIT];
    float M = -INFINITY;
#pragma unroll
    for (int c = 0; c < LSPLIT; ++c) {
      pmv[c] = ws[O_PM + ((size_t)b * LSPLIT + c) * K_ + kk];
      psv[c] = ws[O_PS + ((size_t)b * LSPLIT + c) * K_ + kk];
      M = fmaxf(M, pmv[c]);
    }
    float S = 0.f;
#pragma unroll
    for (int c = 0; c < LSPLIT; ++c) S += psv[c] * expf(pmv[c] - M);
    Al[kk] = expf(pmv[ch] - M) / S;
  }
  __syncthreads();

  const _Float16* lg = reinterpret_cast<const _Float16*>(ws + O_L16) +
                       (size_t)(b * L_ + l0) * K_;
  float a8[8];
#pragma unroll
  for (int i = 0; i < 8; ++i) a8[i] = Al[lane * 8 + i];

  for (int il = 0; il < 32; ++il) {
    int ll = wv * 32 + il;
    f16x8 v = *reinterpret_cast<const f16x8*>(lg + (size_t)ll * K_ + lane * 8);
    float s = 0.f;
#pragma unroll
    for (int i = 0; i < 8; ++i) s += expf((float)v[i]) * a8[i];
#pragma unroll
    for (int off = 32; off > 0; off >>= 1) s += __shfl_xor(s, off);
    if (lane == 0) wl[ll] = s;
  }
  __syncthreads();

  const _Float16* db = reinterpret_cast<const _Float16*>(ws + O_DIR) +
                       (size_t)(b * L_ + l0) * D_;
  int half = tid >> 7;            // 0/1 -> l 0..63 / 64..127
  int dd = (tid & 127) * 4;
  float4 a4 = {0.f, 0.f, 0.f, 0.f};
  for (int l = half * 64; l < half * 64 + 64; ++l) {
    float wgt = wl[l];
    f16x4 dv = *reinterpret_cast<const f16x4*>(db + (size_t)l * D_ + dd);
    a4.x += wgt * (float)dv[0];
    a4.y += wgt * (float)dv[1];
    a4.z += wgt * (float)dv[2];
    a4.w += wgt * (float)dv[3];
  }
  atomicAdd(&ws[O_WX + b * D_ + dd + 0], a4.x);
  atomicAdd(&ws[O_WX + b * D_ + dd + 1], a4.y);
  atomicAdd(&ws[O_WX + b * D_ + dd + 2], a4.z);
  atomicAdd(&ws[O_WX + b * D_ + dd + 3], a4.w);
}

// out[b,d] = (rawscale/L) * (wx/K - meanC[d])
__global__ void k_final(const float* ws, float* out) {
  int i = blockIdx.x * 256 + threadIdx.x;
  int d = i & (D_ - 1);
  out[i] = (ws[O_SCALE + i] * (1.f / L_)) *
           (ws[O_WX + i] * (1.f / K_) - ws[O_MEANC + d]);
}

extern "C" void kernel_launch(void* const* d_in, const int* in_sizes, int n_in,
                              void* d_out, int out_size, void* d_ws, size_t ws_size,
                              hipStream_t stream) {
  const float* x = (const float*)d_in[0];
  const float* cent = (const float*)d_in[1];
  float* out = (float*)d_out;
  float* ws = (float*)d_ws;

  k_prep<<<386, 256, 0, stream>>>(cent, ws);
  k_sqacc<<<dim3(B_, D_ / 256, 8), 256, 0, stream>>>(x, ws);
  k_dir16<<<16384, 256, 0, stream>>>(x, ws);
  k_gemm16<<<dim3(L_ / 128, K_ / 128, B_), 256, 0, stream>>>(ws);
  k_wsumwx<<<dim3(B_, LSPLIT), 256, 0, stream>>>(ws);
  k_final<<<B_ * D_ / 256, 256, 0, stream>>>(ws, out);
}